// Round 15
// baseline (359.612 us; speedup 1.0000x reference)
//
#include <hip/hip_runtime.h>

typedef unsigned short ushort_t;
typedef __attribute__((ext_vector_type(8))) __bf16 bf16x8;
typedef __attribute__((ext_vector_type(4))) float f32x4;
typedef __attribute__((ext_vector_type(4))) ushort_t ushort4_t;

__device__ inline ushort_t f2bf(float f){
  __bf16 h = (__bf16)f;
  union { __bf16 h; ushort_t u; } v; v.h = h;
  return v.u;
}

__device__ inline f32x4 mfma16(bf16x8 a, bf16x8 b, f32x4 c){
  return __builtin_amdgcn_mfma_f32_16x16x32_bf16(a, b, c, 0, 0, 0);
}

// direct global->LDS, 16B per lane; LDS dest wave-uniform base + lane*16
#define GLDS16(gsrc, ldst) \
  __builtin_amdgcn_global_load_lds((const __attribute__((address_space(1))) unsigned int*)(gsrc), \
                                   (__attribute__((address_space(3))) unsigned int*)(ldst), 16, 0, 0)

// ---------------- Kernel A1: spectral norm sigma (one block per weight) ----
__global__ void sigma_kernel(const float* __restrict__ Wf, const float* __restrict__ uf,
                             const float* __restrict__ Wg, const float* __restrict__ ug,
                             const float* __restrict__ Wh, const float* __restrict__ uh,
                             const float* __restrict__ Wc, const float* __restrict__ uc,
                             float* __restrict__ inv_sigma){
  int w = blockIdx.x, t = threadIdx.x;
  const float *W, *u; int Cout;
  if      (w == 0){ W = Wf; u = uf; Cout = 32; }
  else if (w == 1){ W = Wg; u = ug; Cout = 32; }
  else if (w == 2){ W = Wh; u = uh; Cout = 256; }
  else            { W = Wc; u = uc; Cout = 256; }
  __shared__ float su[256], sv[256], red[256];
  su[t] = u[t];
  __syncthreads();
  float v = 0.f;
  if (t < Cout){
    for (int i = 0; i < 256; ++i) v += W[i*Cout + t] * su[i];
  }
  red[t] = (t < Cout) ? v*v : 0.f;
  __syncthreads();
  for (int s = 128; s > 0; s >>= 1){ if (t < s) red[t] += red[t+s]; __syncthreads(); }
  float nv = sqrtf(red[0]) + 1e-12f;
  __syncthreads();
  if (t < Cout) sv[t] = v / nv;
  __syncthreads();
  float wv = 0.f;
  for (int d = 0; d < Cout; ++d) wv += W[t*Cout + d] * sv[d];
  __syncthreads();
  red[t] = wv * wv;
  __syncthreads();
  for (int s = 128; s > 0; s >>= 1){ if (t < s) red[t] += red[t+s]; __syncthreads(); }
  if (t == 0){
    float ss2 = red[0];
    float sig = ss2 / (sqrtf(ss2) + 1e-12f);   // sigma = u_new . (W v)
    inv_sigma[w] = 1.0f / sig;
  }
}

// ---------------- Kernel A2: transpose + 1/sigma fold + bf16 cast ----------
__global__ void prep_weights(const float* __restrict__ Wf, const float* __restrict__ Wg,
                             const float* __restrict__ Wh, const float* __restrict__ Wc,
                             const float* __restrict__ inv_sigma,
                             ushort_t* __restrict__ WallT, ushort_t* __restrict__ WcT){
  int idx = blockIdx.x * 256 + threadIdx.x;   // 0 .. 147455
  if (idx < 81920){                            // WallT[c][k], c in [0,320)
    int c = idx >> 8, k = idx & 255;
    float val, is;
    if (c < 32)      { val = Wf[k*32  + c      ]; is = inv_sigma[0]; }
    else if (c < 64) { val = Wg[k*32  + (c-32) ]; is = inv_sigma[1]; }
    else             { val = Wh[k*256 + (c-64) ]; is = inv_sigma[2]; }
    WallT[idx] = f2bf(val * is);
  } else {
    int j = idx - 81920; int c = j >> 8, k = j & 255;
    WcT[j] = f2bf(Wc[k*256 + c] * inv_sigma[3]);
  }
}

// ---------------- Kernel B: f,g,h = x @ [Wf|Wg|Wh]_sn + bias ---------------
// h is written KEY-PERMUTED within each 64-pixel tile so attention's PV can
// consume P directly from QK^T's register layout (see attn_kernel).
// s(k) = (k&32) | (((k>>2)&3)<<3) | (((k>>4)&1)<<2) | (k&3).
__global__ __launch_bounds__(256) void fgh_kernel(
    const float* __restrict__ x, const ushort_t* __restrict__ WallT,
    const float* __restrict__ bf, const float* __restrict__ bg, const float* __restrict__ bh,
    ushort_t* __restrict__ fO, ushort_t* __restrict__ gO, ushort_t* __restrict__ hT){
  __shared__ __attribute__((aligned(16))) char ldsX[4][16384];  // 16 rows x 1KB per wave
  int t = threadIdx.x;
  int wv = t >> 6, l = t & 63, lrow = l & 15, lgrp = l >> 4;
  long r0 = (long)blockIdx.x * 64 + wv * 16;
  char* ldsW = ldsX[wv];
#pragma unroll
  for (int rloc = 0; rloc < 16; ++rloc){
    const char* src = (const char*)(x + (r0 + rloc)*256)
                    + ((l*16) ^ ((rloc & 7) << 4));
    GLDS16(src, ldsW + rloc*1024);
  }
  asm volatile("s_waitcnt vmcnt(0)" ::: "memory");
  const char* xrow = ldsW + lrow*1024;
  int swzX = (lrow & 7) << 4;
  f32x4 acc[20];
#pragma unroll
  for (int i = 0; i < 20; ++i) acc[i] = f32x4{0.f,0.f,0.f,0.f};
#pragma unroll
  for (int ks = 0; ks < 8; ++ks){
    int bb = ks*128 + lgrp*32;
    f32x4 xa = *(const f32x4*)(xrow + ( bb       ^ swzX));
    f32x4 xb = *(const f32x4*)(xrow + ((bb + 16) ^ swzX));
    union { __bf16 h[8]; bf16x8 v; } A;
#pragma unroll
    for (int j = 0; j < 4; ++j){ A.h[j] = (__bf16)xa[j]; A.h[4+j] = (__bf16)xb[j]; }
    int kk = ks*32 + lgrp*8;
#pragma unroll
    for (int ct = 0; ct < 20; ++ct){
      bf16x8 bbv = *(const bf16x8*)(WallT + (ct*16 + lrow)*256 + kk);
      acc[ct] = mfma16(A.v, bbv, acc[ct]);
    }
  }
#pragma unroll
  for (int ct = 0; ct < 20; ++ct){
    int col = ct*16 + lrow;
    long rowb = r0 + lgrp*4;
    if (col < 32){
      float bv = bf[col];
#pragma unroll
      for (int rg = 0; rg < 4; ++rg) fO[(rowb+rg)*32 + col] = f2bf(acc[ct][rg] + bv);
    } else if (col < 64){
      float bv = bg[col-32];
#pragma unroll
      for (int rg = 0; rg < 4; ++rg)
        gO[(rowb+rg)*32 + (col-32)] = f2bf((acc[ct][rg] + bv) * 1.44269504f);
    } else {
      int hc = col - 64;
      float bv = bh[hc];
      long bb2 = rowb >> 12, n = rowb & 4095;
      int k6 = (int)(n & 63);
      int s6 = (k6 & 32) | (((k6 >> 2) & 3) << 3) | (((k6 >> 4) & 1) << 2) | (k6 & 3);
      long pos = (n & ~63L) | (long)s6;     // rowb%4==0 -> 4 consecutive slots
      ushort4_t pk;
#pragma unroll
      for (int rg = 0; rg < 4; ++rg) pk[rg] = f2bf(acc[ct][rg] + bv);
      *(ushort4_t*)(hT + (bb2*256 + hc)*4096 + pos) = pk;  // [b][d][key-slot]
    }
  }
}

// ---------------- Kernel C: flash attention v9 — ZERO-LDS, barrier-free -----
// grid 512: b = bid&7 (batch pinned to one XCD's L2; V half = 1 MB << 4 MB),
// qt, kh. 4 waves x 32 q, fully independent: V is L2-resident, so the LDS
// staging + vmcnt(0) + 2 barriers/tile of r10 were pure overhead (guide
// common-mistake #7, m169 precedent). PV A-fragments read DIRECTLY from the
// key-permuted hT (contiguous 16B per lane, 64B per row-quad). No LDS, no
// __syncthreads: 2048 decoupled waves mutually hide L2 latency.
__global__ __launch_bounds__(256, 2) void attn_kernel(
    const ushort_t* __restrict__ fI, const ushort_t* __restrict__ gI,
    const ushort_t* __restrict__ hT,
    ushort_t* __restrict__ oP, float* __restrict__ mP, float* __restrict__ liP){
  int bid = blockIdx.x, t = threadIdx.x;
  int b = bid & 7, rest = bid >> 3, qt = rest >> 1, kh = rest & 1;
  int wv = t >> 6, l = t & 63, lrow = l & 15, lgrp = l >> 4;
  int q0 = qt*128 + wv*32;
  long key_base = (long)kh * 2048;
  const ushort_t* gB = gI + ((long)b*4096 + q0)*32;
  bf16x8 qa0 = *(const bf16x8*)(gB + lrow*32 + lgrp*8);
  bf16x8 qa1 = *(const bf16x8*)(gB + (16 + lrow)*32 + lgrp*8);
  const ushort_t* hB = hT + (long)b*256*4096;
  const ushort_t* kp = fI + (long)b*4096*32 + key_base*32 + lrow*32 + lgrp*8;
  // per-lane V base: row d = lrow (+ct*16 via pointer bump), keys lgrp*8..+7
  const ushort_t* vbase = hB + (long)lrow*4096 + key_base + lgrp*8;
  f32x4 o0[16], o1[16];
#pragma unroll
  for (int i = 0; i < 16; ++i){ o0[i] = f32x4{0.f,0.f,0.f,0.f}; o1[i] = f32x4{0.f,0.f,0.f,0.f}; }
  float m0 = -1e30f, m1 = -1e30f, li0 = 0.f, li1 = 0.f;   // per-lane, q = lrow (log2)
  for (int kt = 0; kt < 32; ++kt){
    bf16x8 kb0 = *(const bf16x8*)(kp);
    bf16x8 kb1 = *(const bf16x8*)(kp + 512);
    bf16x8 kb2 = *(const bf16x8*)(kp + 1024);
    bf16x8 kb3 = *(const bf16x8*)(kp + 1536);
    kp += 2048;
    // swapped QK^T: s{qt}{st}[rg] = S[key = st*16+lgrp*4+rg][q = lrow]
    f32x4 z = f32x4{0.f,0.f,0.f,0.f};
    f32x4 s00 = mfma16(kb0, qa0, z);
    f32x4 s01 = mfma16(kb1, qa0, z);
    f32x4 s02 = mfma16(kb2, qa0, z);
    f32x4 s03 = mfma16(kb3, qa0, z);
    f32x4 s10 = mfma16(kb0, qa1, z);
    f32x4 s11 = mfma16(kb1, qa1, z);
    f32x4 s12 = mfma16(kb2, qa1, z);
    f32x4 s13 = mfma16(kb3, qa1, z);
    // local per-lane max only (no shuffles in common path)
    float tm0 = -1e30f, tm1 = -1e30f;
#pragma unroll
    for (int rg = 0; rg < 4; ++rg){
      tm0 = fmaxf(tm0, fmaxf(fmaxf(s00[rg], s01[rg]), fmaxf(s02[rg], s03[rg])));
      tm1 = fmaxf(tm1, fmaxf(fmaxf(s10[rg], s11[rg]), fmaxf(s12[rg], s13[rg])));
    }
    if (__any((tm0 > m0 + 8.f) || (tm1 > m1 + 8.f))){   // defer-max (T13)
      tm0 = fmaxf(tm0, __shfl_xor(tm0, 16)); tm0 = fmaxf(tm0, __shfl_xor(tm0, 32));
      tm1 = fmaxf(tm1, __shfl_xor(tm1, 16)); tm1 = fmaxf(tm1, __shfl_xor(tm1, 32));
      float mn0 = fmaxf(m0, tm0), mn1 = fmaxf(m1, tm1);
      float sc0 = exp2f(m0 - mn0), sc1 = exp2f(m1 - mn1);
      m0 = mn0; m1 = mn1; li0 *= sc0; li1 *= sc1;
#pragma unroll
      for (int ct = 0; ct < 16; ++ct)
#pragma unroll
        for (int rg = 0; rg < 4; ++rg){ o0[ct][rg] *= sc0; o1[ct][rg] *= sc1; }
    }
    // P = exp2(s-m) -> PV B-fragments entirely in registers.
    union { __bf16 h[8]; bf16x8 v; } pf00, pf01, pf10, pf11;
#pragma unroll
    for (int rg = 0; rg < 4; ++rg){
      float a0 = exp2f(s00[rg] - m0), a1 = exp2f(s01[rg] - m0);
      float a2 = exp2f(s02[rg] - m0), a3 = exp2f(s03[rg] - m0);
      li0 += (a0 + a1) + (a2 + a3);
      pf00.h[rg] = (__bf16)a0; pf00.h[4+rg] = (__bf16)a1;
      pf01.h[rg] = (__bf16)a2; pf01.h[4+rg] = (__bf16)a3;
      float c0 = exp2f(s10[rg] - m1), c1 = exp2f(s11[rg] - m1);
      float c2 = exp2f(s12[rg] - m1), c3 = exp2f(s13[rg] - m1);
      li1 += (c0 + c1) + (c2 + c3);
      pf10.h[rg] = (__bf16)c0; pf10.h[4+rg] = (__bf16)c1;
      pf11.h[rg] = (__bf16)c2; pf11.h[4+rg] = (__bf16)c3;
    }
    // PV: A-fragments straight from L2-resident hT (key-permuted layout
    // makes each lane's 8 k-elements a contiguous 16B read).
    const ushort_t* vp = vbase + kt*64;
    __builtin_amdgcn_s_setprio(1);
#pragma unroll
    for (int ct = 0; ct < 16; ++ct){
      bf16x8 vb0 = *(const bf16x8*)(vp);
      bf16x8 vb1 = *(const bf16x8*)(vp + 32);
      vp += 16*4096;                       // next d-row block (ct+1)*16
      o0[ct] = mfma16(vb0, pf00.v, o0[ct]);   // vb reused across both q-tiles
      o0[ct] = mfma16(vb1, pf01.v, o0[ct]);
      o1[ct] = mfma16(vb0, pf10.v, o1[ct]);
      o1[ct] = mfma16(vb1, pf11.v, o1[ct]);
    }
    __builtin_amdgcn_s_setprio(0);
  }
  li0 += __shfl_xor(li0, 16); li0 += __shfl_xor(li0, 32);
  li1 += __shfl_xor(li1, 16); li1 += __shfl_xor(li1, 32);
  long rbase = (long)b*4096 + q0;
  ushort_t* Ob = oP + ((long)kh*32768 + rbase)*256;
  // D layout: col = q = lrow(+16 for qt1), row = d = ct*16 + lgrp*4 + rg
#pragma unroll
  for (int ct = 0; ct < 16; ++ct){
    ushort4_t pk0, pk1;
#pragma unroll
    for (int rg = 0; rg < 4; ++rg){ pk0[rg] = f2bf(o0[ct][rg]); pk1[rg] = f2bf(o1[ct][rg]); }
    *(ushort4_t*)(Ob + (long)lrow*256      + ct*16 + lgrp*4) = pk0;
    *(ushort4_t*)(Ob + (long)(16+lrow)*256 + ct*16 + lgrp*4) = pk1;
  }
  if (l < 16){
    mP [kh*32768 + rbase + lrow]      = m0;
    liP[kh*32768 + rbase + lrow]      = li0;
    mP [kh*32768 + rbase + 16 + lrow] = m1;
    liP[kh*32768 + rbase + 16 + lrow] = li1;
  }
}

// ---------------- Kernel D: combine split-K + out = gamma*(O@Wc + bc) + x --
__global__ __launch_bounds__(256) void out_kernel(
    const ushort_t* __restrict__ oP, const float* __restrict__ mP,
    const float* __restrict__ liP, const ushort_t* __restrict__ WcT,
    const float* __restrict__ bc, const float* __restrict__ x,
    const float* __restrict__ gamma, float* __restrict__ out){
  __shared__ __attribute__((aligned(16))) char ldsO[4][16384]; // per wave: o1 8KB | o2 8KB
  int t = threadIdx.x;
  int wv = t >> 6, l = t & 63, lrow = l & 15, lgrp = l >> 4;
  long r0 = (long)blockIdx.x * 64 + wv * 16;
  char* ldsW = ldsO[wv];
#pragma unroll
  for (int i = 0; i < 8; ++i){
    int rloc = 2*i + (l >> 5);
    int soff = ((l & 31)*16) ^ ((rloc & 7) << 4);
    GLDS16((const char*)(oP + (r0 + rloc)*256) + soff,            ldsW + i*1024);
    GLDS16((const char*)(oP + (32768L + r0 + rloc)*256) + soff,   ldsW + 8192 + i*1024);
  }
  long r = r0 + lrow;
  float m1 = mP[r],  m2 = mP[32768 + r];
  float li1 = liP[r], li2 = liP[32768 + r];
  float mm  = fmaxf(m1, m2);
  float sc1 = exp2f(m1 - mm), sc2 = exp2f(m2 - mm);
  float inv = 1.0f / (li1*sc1 + li2*sc2);
  float w1 = sc1 * inv, w2 = sc2 * inv;
  asm volatile("s_waitcnt vmcnt(0)" ::: "memory");
  const char* orow = ldsW + lrow*512;
  int swzO = (lrow & 7) << 4;
  f32x4 acc[16];
#pragma unroll
  for (int i = 0; i < 16; ++i) acc[i] = f32x4{0.f,0.f,0.f,0.f};
#pragma unroll
  for (int ks = 0; ks < 8; ++ks){
    int bb = (ks*64 + lgrp*16) ^ swzO;
    bf16x8 a1 = *(const bf16x8*)(orow + bb);
    bf16x8 a2 = *(const bf16x8*)(orow + 8192 + bb);
    union { __bf16 h[8]; bf16x8 v; } A;
#pragma unroll
    for (int j = 0; j < 8; ++j)
      A.h[j] = (__bf16)((float)a1[j]*w1 + (float)a2[j]*w2);
    int kk = ks*32 + lgrp*8;
#pragma unroll
    for (int ct = 0; ct < 16; ++ct){
      bf16x8 bbv = *(const bf16x8*)(WcT + (ct*16 + lrow)*256 + kk);
      acc[ct] = mfma16(A.v, bbv, acc[ct]);
    }
  }
  float gm = gamma[0];
#pragma unroll
  for (int ct = 0; ct < 16; ++ct){
    int col = ct*16 + lrow;
    float bv = bc[col];
#pragma unroll
    for (int rg = 0; rg < 4; ++rg){
      long row = r0 + lgrp*4 + rg;
      out[row*256 + col] = gm*(acc[ct][rg] + bv) + x[row*256 + col];
    }
  }
}

extern "C" void kernel_launch(void* const* d_in, const int* in_sizes, int n_in,
                              void* d_out, int out_size, void* d_ws, size_t ws_size,
                              hipStream_t stream){
  (void)in_sizes; (void)n_in; (void)out_size; (void)ws_size;
  const float* x  = (const float*)d_in[0];
  const float* Wf = (const float*)d_in[1];
  const float* bf = (const float*)d_in[2];
  const float* uf = (const float*)d_in[3];
  const float* Wg = (const float*)d_in[4];
  const float* bg = (const float*)d_in[5];
  const float* ug = (const float*)d_in[6];
  const float* Wh = (const float*)d_in[7];
  const float* bh = (const float*)d_in[8];
  const float* uh = (const float*)d_in[9];
  const float* Wc = (const float*)d_in[10];
  const float* bc = (const float*)d_in[11];
  const float* uc = (const float*)d_in[12];
  const float* gamma = (const float*)d_in[13];
  float* out = (float*)d_out;

  char* w = (char*)d_ws;
  float*    inv_sigma = (float*)w;                         // @0,     256 B
  ushort_t* WallT = (ushort_t*)(w + 256);                  // 163840
  ushort_t* WcT   = (ushort_t*)(w + 164096);               // 131072
  ushort_t* fW    = (ushort_t*)(w + 295168);               // 2 MB
  ushort_t* gW    = (ushort_t*)(w + 2392320);              // 2 MB
  ushort_t* hTW   = (ushort_t*)(w + 4489472);              // 16 MB (key-permuted)
  ushort_t* oPW   = (ushort_t*)(w + 21266688);             // 32 MB (2 x 8x4096x256 bf16)
  float*    mPW   = (float*)   (w + 54821120);             // 256 KB
  float*    liPW  = (float*)   (w + 55083264);             // 256 KB  -> total ~55.3 MB

  hipLaunchKernelGGL(sigma_kernel, dim3(4),    dim3(256), 0, stream,
                     Wf, uf, Wg, ug, Wh, uh, Wc, uc, inv_sigma);
  hipLaunchKernelGGL(prep_weights, dim3(576),  dim3(256), 0, stream,
                     Wf, Wg, Wh, Wc, inv_sigma, WallT, WcT);
  hipLaunchKernelGGL(fgh_kernel,   dim3(512),  dim3(256), 0, stream,
                     x, WallT, bf, bg, bh, fW, gW, hTW);
  hipLaunchKernelGGL(attn_kernel,  dim3(512),  dim3(256), 0, stream,
                     fW, gW, hTW, oPW, mPW, liPW);
  hipLaunchKernelGGL(out_kernel,   dim3(512),  dim3(256), 0, stream,
                     oPW, mPW, liPW, WcT, bc, x, gamma, out);
}

// Round 16
// 202.782 us; speedup vs baseline: 1.7734x; 1.7734x over previous
//
#include <hip/hip_runtime.h>

typedef unsigned short ushort_t;
typedef __attribute__((ext_vector_type(8))) __bf16 bf16x8;
typedef __attribute__((ext_vector_type(4))) float f32x4;
typedef __attribute__((ext_vector_type(4))) ushort_t ushort4_t;

__device__ inline ushort_t f2bf(float f){
  __bf16 h = (__bf16)f;
  union { __bf16 h; ushort_t u; } v; v.h = h;
  return v.u;
}

__device__ inline f32x4 mfma16(bf16x8 a, bf16x8 b, f32x4 c){
  return __builtin_amdgcn_mfma_f32_16x16x32_bf16(a, b, c, 0, 0, 0);
}

// direct global->LDS, 16B per lane; LDS dest wave-uniform base + lane*16
#define GLDS16(gsrc, ldst) \
  __builtin_amdgcn_global_load_lds((const __attribute__((address_space(1))) unsigned int*)(gsrc), \
                                   (__attribute__((address_space(3))) unsigned int*)(ldst), 16, 0, 0)

// ---------------- Kernel A1: spectral norm sigma (one block per weight) ----
__global__ void sigma_kernel(const float* __restrict__ Wf, const float* __restrict__ uf,
                             const float* __restrict__ Wg, const float* __restrict__ ug,
                             const float* __restrict__ Wh, const float* __restrict__ uh,
                             const float* __restrict__ Wc, const float* __restrict__ uc,
                             float* __restrict__ inv_sigma){
  int w = blockIdx.x, t = threadIdx.x;
  const float *W, *u; int Cout;
  if      (w == 0){ W = Wf; u = uf; Cout = 32; }
  else if (w == 1){ W = Wg; u = ug; Cout = 32; }
  else if (w == 2){ W = Wh; u = uh; Cout = 256; }
  else            { W = Wc; u = uc; Cout = 256; }
  __shared__ float su[256], sv[256], red[256];
  su[t] = u[t];
  __syncthreads();
  float v = 0.f;
  if (t < Cout){
    for (int i = 0; i < 256; ++i) v += W[i*Cout + t] * su[i];
  }
  red[t] = (t < Cout) ? v*v : 0.f;
  __syncthreads();
  for (int s = 128; s > 0; s >>= 1){ if (t < s) red[t] += red[t+s]; __syncthreads(); }
  float nv = sqrtf(red[0]) + 1e-12f;
  __syncthreads();
  if (t < Cout) sv[t] = v / nv;
  __syncthreads();
  float wv = 0.f;
  for (int d = 0; d < Cout; ++d) wv += W[t*Cout + d] * sv[d];
  __syncthreads();
  red[t] = wv * wv;
  __syncthreads();
  for (int s = 128; s > 0; s >>= 1){ if (t < s) red[t] += red[t+s]; __syncthreads(); }
  if (t == 0){
    float ss2 = red[0];
    float sig = ss2 / (sqrtf(ss2) + 1e-12f);   // sigma = u_new . (W v)
    inv_sigma[w] = 1.0f / sig;
  }
}

// ---------------- Kernel A2: transpose + 1/sigma fold + bf16 cast ----------
__global__ void prep_weights(const float* __restrict__ Wf, const float* __restrict__ Wg,
                             const float* __restrict__ Wh, const float* __restrict__ Wc,
                             const float* __restrict__ inv_sigma,
                             ushort_t* __restrict__ WallT, ushort_t* __restrict__ WcT){
  int idx = blockIdx.x * 256 + threadIdx.x;   // 0 .. 147455
  if (idx < 81920){                            // WallT[c][k], c in [0,320)
    int c = idx >> 8, k = idx & 255;
    float val, is;
    if (c < 32)      { val = Wf[k*32  + c      ]; is = inv_sigma[0]; }
    else if (c < 64) { val = Wg[k*32  + (c-32) ]; is = inv_sigma[1]; }
    else             { val = Wh[k*256 + (c-64) ]; is = inv_sigma[2]; }
    WallT[idx] = f2bf(val * is);
  } else {
    int j = idx - 81920; int c = j >> 8, k = j & 255;
    WcT[j] = f2bf(Wc[k*256 + c] * inv_sigma[3]);
  }
}

// ---------------- Kernel B: f,g,h = x @ [Wf|Wg|Wh]_sn + bias ---------------
// h is written KEY-PERMUTED within each 64-pixel tile so attention's PV can
// consume P directly from QK^T's register layout (see attn_kernel).
// s(k) = (k&32) | (((k>>2)&3)<<3) | (((k>>4)&1)<<2) | (k&3).
__global__ __launch_bounds__(256) void fgh_kernel(
    const float* __restrict__ x, const ushort_t* __restrict__ WallT,
    const float* __restrict__ bf, const float* __restrict__ bg, const float* __restrict__ bh,
    ushort_t* __restrict__ fO, ushort_t* __restrict__ gO, ushort_t* __restrict__ hT){
  __shared__ __attribute__((aligned(16))) char ldsX[4][16384];  // 16 rows x 1KB per wave
  int t = threadIdx.x;
  int wv = t >> 6, l = t & 63, lrow = l & 15, lgrp = l >> 4;
  long r0 = (long)blockIdx.x * 64 + wv * 16;
  char* ldsW = ldsX[wv];
#pragma unroll
  for (int rloc = 0; rloc < 16; ++rloc){
    const char* src = (const char*)(x + (r0 + rloc)*256)
                    + ((l*16) ^ ((rloc & 7) << 4));
    GLDS16(src, ldsW + rloc*1024);
  }
  asm volatile("s_waitcnt vmcnt(0)" ::: "memory");
  const char* xrow = ldsW + lrow*1024;
  int swzX = (lrow & 7) << 4;
  f32x4 acc[20];
#pragma unroll
  for (int i = 0; i < 20; ++i) acc[i] = f32x4{0.f,0.f,0.f,0.f};
#pragma unroll
  for (int ks = 0; ks < 8; ++ks){
    int bb = ks*128 + lgrp*32;
    f32x4 xa = *(const f32x4*)(xrow + ( bb       ^ swzX));
    f32x4 xb = *(const f32x4*)(xrow + ((bb + 16) ^ swzX));
    union { __bf16 h[8]; bf16x8 v; } A;
#pragma unroll
    for (int j = 0; j < 4; ++j){ A.h[j] = (__bf16)xa[j]; A.h[4+j] = (__bf16)xb[j]; }
    int kk = ks*32 + lgrp*8;
#pragma unroll
    for (int ct = 0; ct < 20; ++ct){
      bf16x8 bbv = *(const bf16x8*)(WallT + (ct*16 + lrow)*256 + kk);
      acc[ct] = mfma16(A.v, bbv, acc[ct]);
    }
  }
#pragma unroll
  for (int ct = 0; ct < 20; ++ct){
    int col = ct*16 + lrow;
    long rowb = r0 + lgrp*4;
    if (col < 32){
      float bv = bf[col];
#pragma unroll
      for (int rg = 0; rg < 4; ++rg) fO[(rowb+rg)*32 + col] = f2bf(acc[ct][rg] + bv);
    } else if (col < 64){
      float bv = bg[col-32];
#pragma unroll
      for (int rg = 0; rg < 4; ++rg)
        gO[(rowb+rg)*32 + (col-32)] = f2bf((acc[ct][rg] + bv) * 1.44269504f);
    } else {
      int hc = col - 64;
      float bv = bh[hc];
      long bb2 = rowb >> 12, n = rowb & 4095;
      int k6 = (int)(n & 63);
      int s6 = (k6 & 32) | (((k6 >> 2) & 3) << 3) | (((k6 >> 4) & 1) << 2) | (k6 & 3);
      long pos = (n & ~63L) | (long)s6;     // rowb%4==0 -> 4 consecutive slots
      ushort4_t pk;
#pragma unroll
      for (int rg = 0; rg < 4; ++rg) pk[rg] = f2bf(acc[ct][rg] + bv);
      *(ushort4_t*)(hT + (bb2*256 + hc)*4096 + pos) = pk;  // [b][d][key-slot]
    }
  }
}

// ---------------- Kernel C: flash attention (round-10 best, final) ----------
// grid 512: b = bid&7, qt = (bid>>3)>>1 (128 q/block), kh = &1.
// 4 waves x 32 q (2 q-tiles, each V b128 LDS read feeds 2 MFMAs). P in regs
// via key-permuted V. Common path uses LOCAL per-lane max + __any only; the
// cross-lane max shuffles run only inside the rare violation branch.
__global__ __launch_bounds__(256, 2) void attn_kernel(
    const ushort_t* __restrict__ fI, const ushort_t* __restrict__ gI,
    const ushort_t* __restrict__ hT,
    ushort_t* __restrict__ oP, float* __restrict__ mP, float* __restrict__ liP){
  __shared__ ushort_t ldsV[256*64];        // 32 KB: [d][key-slot], XOR-swizzled
  int bid = blockIdx.x, t = threadIdx.x;
  int b = bid & 7, rest = bid >> 3, qt = rest >> 1, kh = rest & 1;
  int wv = t >> 6, l = t & 63, lrow = l & 15, lgrp = l >> 4;
  int q0 = qt*128 + wv*32;
  long key_base = (long)kh * 2048;
  const ushort_t* gB = gI + ((long)b*4096 + q0)*32;
  bf16x8 qa0 = *(const bf16x8*)(gB + lrow*32 + lgrp*8);
  bf16x8 qa1 = *(const bf16x8*)(gB + (16 + lrow)*32 + lgrp*8);
  const ushort_t* hB = hT + (long)b*256*4096;
  const ushort_t* kp = fI + (long)b*4096*32 + key_base*32 + lrow*32 + lgrp*8;
  const ushort_t* vsrc = hB + (long)(wv*64 + (l>>3))*4096 + key_base
                            + (((l & 7) ^ (l >> 3)) << 3);
  ushort_t* vdst = ldsV + wv*4096;
  f32x4 o0[16], o1[16];
#pragma unroll
  for (int i = 0; i < 16; ++i){ o0[i] = f32x4{0.f,0.f,0.f,0.f}; o1[i] = f32x4{0.f,0.f,0.f,0.f}; }
  float m0 = -1e30f, m1 = -1e30f, li0 = 0.f, li1 = 0.f;   // per-lane, q = lrow (log2)
  int swzR = (lrow & 7) << 3;
  for (int kt = 0; kt < 32; ++kt){
    __syncthreads();                       // prev tile's ldsV reads complete
    bf16x8 kb0 = *(const bf16x8*)(kp);
    bf16x8 kb1 = *(const bf16x8*)(kp + 512);
    bf16x8 kb2 = *(const bf16x8*)(kp + 1024);
    bf16x8 kb3 = *(const bf16x8*)(kp + 1536);
    kp += 2048;
    const ushort_t* vs = vsrc + kt*64;
#pragma unroll
    for (int i = 0; i < 8; ++i)
      GLDS16(vs + i*32768, vdst + i*512);
    // swapped QK^T: s{qt}{st}[rg] = S[key = st*16+lgrp*4+rg][q = lrow]
    f32x4 z = f32x4{0.f,0.f,0.f,0.f};
    f32x4 s00 = mfma16(kb0, qa0, z);
    f32x4 s01 = mfma16(kb1, qa0, z);
    f32x4 s02 = mfma16(kb2, qa0, z);
    f32x4 s03 = mfma16(kb3, qa0, z);
    f32x4 s10 = mfma16(kb0, qa1, z);
    f32x4 s11 = mfma16(kb1, qa1, z);
    f32x4 s12 = mfma16(kb2, qa1, z);
    f32x4 s13 = mfma16(kb3, qa1, z);
    // local per-lane max only (no shuffles in common path)
    float tm0 = -1e30f, tm1 = -1e30f;
#pragma unroll
    for (int rg = 0; rg < 4; ++rg){
      tm0 = fmaxf(tm0, fmaxf(fmaxf(s00[rg], s01[rg]), fmaxf(s02[rg], s03[rg])));
      tm1 = fmaxf(tm1, fmaxf(fmaxf(s10[rg], s11[rg]), fmaxf(s12[rg], s13[rg])));
    }
    if (__any((tm0 > m0 + 8.f) || (tm1 > m1 + 8.f))){   // defer-max (T13)
      tm0 = fmaxf(tm0, __shfl_xor(tm0, 16)); tm0 = fmaxf(tm0, __shfl_xor(tm0, 32));
      tm1 = fmaxf(tm1, __shfl_xor(tm1, 16)); tm1 = fmaxf(tm1, __shfl_xor(tm1, 32));
      float mn0 = fmaxf(m0, tm0), mn1 = fmaxf(m1, tm1);
      float sc0 = exp2f(m0 - mn0), sc1 = exp2f(m1 - mn1);
      m0 = mn0; m1 = mn1; li0 *= sc0; li1 *= sc1;
#pragma unroll
      for (int ct = 0; ct < 16; ++ct)
#pragma unroll
        for (int rg = 0; rg < 4; ++rg){ o0[ct][rg] *= sc0; o1[ct][rg] *= sc1; }
    }
    // P = exp2(s-m) -> PV B-fragments entirely in registers.
    union { __bf16 h[8]; bf16x8 v; } pf00, pf01, pf10, pf11;
#pragma unroll
    for (int rg = 0; rg < 4; ++rg){
      float a0 = exp2f(s00[rg] - m0), a1 = exp2f(s01[rg] - m0);
      float a2 = exp2f(s02[rg] - m0), a3 = exp2f(s03[rg] - m0);
      li0 += (a0 + a1) + (a2 + a3);
      pf00.h[rg] = (__bf16)a0; pf00.h[4+rg] = (__bf16)a1;
      pf01.h[rg] = (__bf16)a2; pf01.h[4+rg] = (__bf16)a3;
      float c0 = exp2f(s10[rg] - m1), c1 = exp2f(s11[rg] - m1);
      float c2 = exp2f(s12[rg] - m1), c3 = exp2f(s13[rg] - m1);
      li1 += (c0 + c1) + (c2 + c3);
      pf10.h[rg] = (__bf16)c0; pf10.h[4+rg] = (__bf16)c1;
      pf11.h[rg] = (__bf16)c2; pf11.h[4+rg] = (__bf16)c3;
    }
    asm volatile("s_waitcnt vmcnt(0)" ::: "memory");   // V tile landed in LDS
    __syncthreads();                       // all waves' V visible
    __builtin_amdgcn_s_setprio(1);
#pragma unroll
    for (int ct = 0; ct < 16; ++ct){
      int base = (ct*16 + lrow) << 6;
      bf16x8 vb0 = *(const bf16x8*)(ldsV + base + (( (lgrp << 3))      ^ swzR));
      bf16x8 vb1 = *(const bf16x8*)(ldsV + base + ((32 + (lgrp << 3)) ^ swzR));
      o0[ct] = mfma16(vb0, pf00.v, o0[ct]);   // vb reused across both q-tiles
      o0[ct] = mfma16(vb1, pf01.v, o0[ct]);
      o1[ct] = mfma16(vb0, pf10.v, o1[ct]);
      o1[ct] = mfma16(vb1, pf11.v, o1[ct]);
    }
    __builtin_amdgcn_s_setprio(0);
  }
  li0 += __shfl_xor(li0, 16); li0 += __shfl_xor(li0, 32);
  li1 += __shfl_xor(li1, 16); li1 += __shfl_xor(li1, 32);
  long rbase = (long)b*4096 + q0;
  ushort_t* Ob = oP + ((long)kh*32768 + rbase)*256;
  // D layout: col = q = lrow(+16 for qt1), row = d = ct*16 + lgrp*4 + rg
#pragma unroll
  for (int ct = 0; ct < 16; ++ct){
    ushort4_t pk0, pk1;
#pragma unroll
    for (int rg = 0; rg < 4; ++rg){ pk0[rg] = f2bf(o0[ct][rg]); pk1[rg] = f2bf(o1[ct][rg]); }
    *(ushort4_t*)(Ob + (long)lrow*256      + ct*16 + lgrp*4) = pk0;
    *(ushort4_t*)(Ob + (long)(16+lrow)*256 + ct*16 + lgrp*4) = pk1;
  }
  if (l < 16){
    mP [kh*32768 + rbase + lrow]      = m0;
    liP[kh*32768 + rbase + lrow]      = li0;
    mP [kh*32768 + rbase + 16 + lrow] = m1;
    liP[kh*32768 + rbase + 16 + lrow] = li1;
  }
}

// ---------------- Kernel D: combine split-K + out = gamma*(O@Wc + bc) + x --
__global__ __launch_bounds__(256) void out_kernel(
    const ushort_t* __restrict__ oP, const float* __restrict__ mP,
    const float* __restrict__ liP, const ushort_t* __restrict__ WcT,
    const float* __restrict__ bc, const float* __restrict__ x,
    const float* __restrict__ gamma, float* __restrict__ out){
  __shared__ __attribute__((aligned(16))) char ldsO[4][16384]; // per wave: o1 8KB | o2 8KB
  int t = threadIdx.x;
  int wv = t >> 6, l = t & 63, lrow = l & 15, lgrp = l >> 4;
  long r0 = (long)blockIdx.x * 64 + wv * 16;
  char* ldsW = ldsO[wv];
#pragma unroll
  for (int i = 0; i < 8; ++i){
    int rloc = 2*i + (l >> 5);
    int soff = ((l & 31)*16) ^ ((rloc & 7) << 4);
    GLDS16((const char*)(oP + (r0 + rloc)*256) + soff,            ldsW + i*1024);
    GLDS16((const char*)(oP + (32768L + r0 + rloc)*256) + soff,   ldsW + 8192 + i*1024);
  }
  long r = r0 + lrow;
  float m1 = mP[r],  m2 = mP[32768 + r];
  float li1 = liP[r], li2 = liP[32768 + r];
  float mm  = fmaxf(m1, m2);
  float sc1 = exp2f(m1 - mm), sc2 = exp2f(m2 - mm);
  float inv = 1.0f / (li1*sc1 + li2*sc2);
  float w1 = sc1 * inv, w2 = sc2 * inv;
  asm volatile("s_waitcnt vmcnt(0)" ::: "memory");
  const char* orow = ldsW + lrow*512;
  int swzO = (lrow & 7) << 4;
  f32x4 acc[16];
#pragma unroll
  for (int i = 0; i < 16; ++i) acc[i] = f32x4{0.f,0.f,0.f,0.f};
#pragma unroll
  for (int ks = 0; ks < 8; ++ks){
    int bb = (ks*64 + lgrp*16) ^ swzO;
    bf16x8 a1 = *(const bf16x8*)(orow + bb);
    bf16x8 a2 = *(const bf16x8*)(orow + 8192 + bb);
    union { __bf16 h[8]; bf16x8 v; } A;
#pragma unroll
    for (int j = 0; j < 8; ++j)
      A.h[j] = (__bf16)((float)a1[j]*w1 + (float)a2[j]*w2);
    int kk = ks*32 + lgrp*8;
#pragma unroll
    for (int ct = 0; ct < 16; ++ct){
      bf16x8 bbv = *(const bf16x8*)(WcT + (ct*16 + lrow)*256 + kk);
      acc[ct] = mfma16(A.v, bbv, acc[ct]);
    }
  }
  float gm = gamma[0];
#pragma unroll
  for (int ct = 0; ct < 16; ++ct){
    int col = ct*16 + lrow;
    float bv = bc[col];
#pragma unroll
    for (int rg = 0; rg < 4; ++rg){
      long row = r0 + lgrp*4 + rg;
      out[row*256 + col] = gm*(acc[ct][rg] + bv) + x[row*256 + col];
    }
  }
}

extern "C" void kernel_launch(void* const* d_in, const int* in_sizes, int n_in,
                              void* d_out, int out_size, void* d_ws, size_t ws_size,
                              hipStream_t stream){
  (void)in_sizes; (void)n_in; (void)out_size; (void)ws_size;
  const float* x  = (const float*)d_in[0];
  const float* Wf = (const float*)d_in[1];
  const float* bf = (const float*)d_in[2];
  const float* uf = (const float*)d_in[3];
  const float* Wg = (const float*)d_in[4];
  const float* bg = (const float*)d_in[5];
  const float* ug = (const float*)d_in[6];
  const float* Wh = (const float*)d_in[7];
  const float* bh = (const float*)d_in[8];
  const float* uh = (const float*)d_in[9];
  const float* Wc = (const float*)d_in[10];
  const float* bc = (const float*)d_in[11];
  const float* uc = (const float*)d_in[12];
  const float* gamma = (const float*)d_in[13];
  float* out = (float*)d_out;

  char* w = (char*)d_ws;
  float*    inv_sigma = (float*)w;                         // @0,     256 B
  ushort_t* WallT = (ushort_t*)(w + 256);                  // 163840
  ushort_t* WcT   = (ushort_t*)(w + 164096);               // 131072
  ushort_t* fW    = (ushort_t*)(w + 295168);               // 2 MB
  ushort_t* gW    = (ushort_t*)(w + 2392320);              // 2 MB
  ushort_t* hTW   = (ushort_t*)(w + 4489472);              // 16 MB (key-permuted)
  ushort_t* oPW   = (ushort_t*)(w + 21266688);             // 32 MB (2 x 8x4096x256 bf16)
  float*    mPW   = (float*)   (w + 54821120);             // 256 KB
  float*    liPW  = (float*)   (w + 55083264);             // 256 KB  -> total ~55.3 MB

  hipLaunchKernelGGL(sigma_kernel, dim3(4),    dim3(256), 0, stream,
                     Wf, uf, Wg, ug, Wh, uh, Wc, uc, inv_sigma);
  hipLaunchKernelGGL(prep_weights, dim3(576),  dim3(256), 0, stream,
                     Wf, Wg, Wh, Wc, inv_sigma, WallT, WcT);
  hipLaunchKernelGGL(fgh_kernel,   dim3(512),  dim3(256), 0, stream,
                     x, WallT, bf, bg, bh, fW, gW, hTW);
  hipLaunchKernelGGL(attn_kernel,  dim3(512),  dim3(256), 0, stream,
                     fW, gW, hTW, oPW, mPW, liPW);
  hipLaunchKernelGGL(out_kernel,   dim3(512),  dim3(256), 0, stream,
                     oPW, mPW, liPW, WcT, bc, x, gamma, out);
}